// Round 9
// baseline (127.235 us; speedup 1.0000x reference)
//
#include <hip/hip_runtime.h>

// ---- problem constants ----
#define KW 11
#define NB 2            // N * C
#define DI 96
#define HI 256
#define WI 256
#define DOUT 86
#define HOUT 246
#define WOUT 246
#define HT 16           // output tile height
#define WT 16           // output tile width
#define DCH 4           // chunks along D
#define DPC 22          // output d per chunk (22,22,22,20)
#define RR 26           // HT + KW - 1 region rows
#define HSZ (HI * WI)
#define SSIM_C1 1e-4f
#define SSIM_C2 9e-4f
#define NBLK (16 * 16 * NB * DCH)   // 2048
// raw pair buffer: 2 slices x 26 rows x [7 img1 chunks | 7 img2 chunks | 1 pad]
// x 16B. Row stride 15 slots (60 floats): phase-A b128 reads then spread as
// bank-group (m - r - half) & 7 -> all 8 groups evenly = b128 floor, no
// swizzle and no XOR address math. Double-buffered pairs (pipeline).
#define ROW_SLOT 15
#define SLICE_SLOT (RR * ROW_SLOT)   // 390
#define PAIR_SLOT (2 * SLICE_SLOT)   // 780
#define SLICE_F (SLICE_SLOT * 4)     // 1560 floats
#define PAIR_F (PAIR_SLOT * 4)       // 3120 floats
#define NSTG 4

typedef const unsigned int __attribute__((address_space(1)))* gp1_t;
typedef unsigned int __attribute__((address_space(3)))* lp3_t;
using f32x2 = __attribute__((ext_vector_type(2))) float;
using f32x4 = __attribute__((ext_vector_type(4))) float;

__device__ __forceinline__ void gl_lds16(const float* g, float* l) {
    __builtin_amdgcn_global_load_lds((gp1_t)(const void*)g, (lp3_t)(void*)l, 16, 0, 0);
}

// packed fp32 FMA, wave-uniform weight in SGPR pair.
__device__ __forceinline__ f32x2 pk_fma_s(f32x2 w, f32x2 x, f32x2 acc) {
    f32x2 d;
    asm("v_pk_fma_f32 %0, %1, %2, %3" : "=v"(d) : "s"(w), "v"(x), "v"(acc));
    return d;
}

__device__ __forceinline__ float rfl(float x) {
    return __int_as_float(__builtin_amdgcn_readfirstlane(__float_as_int(x)));
}

// Packed ring-buffer D-conv step, compile-time slot indices.
template<int J>
__device__ __forceinline__ void acc_step(
    f32x2 (&AB)[KW], f32x2 (&PQ)[KW], const f32x2 (&w2)[KW],
    f32x2 f12, f32x2 f34, bool emit, f32x2& o12, f32x2& o34)
{
    #pragma unroll
    for (int p = 0; p < KW; ++p) {
        const int s = (J - p + KW) % KW;   // compile-time
        AB[s] = pk_fma_s(w2[p], f12, AB[s]);
        PQ[s] = pk_fma_s(w2[p], f34, PQ[s]);
    }
    const int C = (J + 1) % KW;
    if (emit) { o12 = AB[C]; o34 = PQ[C]; }
    AB[C] = (f32x2){0.f, 0.f};
    PQ[C] = (f32x2){0.f, 0.f};
}

// NOTE: min-waves/EU = 2 (VGPR cap 256). (256,4) caps VGPRs at 64 -> massive
// spill (R4). Vertical coarsening (2 rings/thread) also spills (R7).
static __global__ __launch_bounds__(256, 2) void ssim_main(
    const float* __restrict__ img1, const float* __restrict__ img2,
    const float* __restrict__ win, float* __restrict__ bsum)
{
    __shared__ __align__(16) float rawf[2 * PAIR_F];        // 24960 B (dbuf)
    __shared__ __align__(16) float a4pool[2 * 2 * RR * 17 * 4];  // 28288 B (dbuf)
    // A4[pb][sl][r][c], stride 17 f32x4/row (bank-floor for write & read).
    #define A4AT(pb, sl, r, c) \
        (((f32x4*)a4pool)[((((pb) * 2 + (sl)) * RR) + (r)) * 17 + (c)])
    // w-profile scratch aliased into a4pool (dead before first phase A / after loop)
    float* const tmpw = a4pool;          // 121 floats
    float* const w1s  = a4pool + 128;    // 11 floats
    float* const red  = a4pool + 140;    // 4 floats (used after loop only)

    const int t = threadIdx.x;
    const int bz = blockIdx.z;            // n*4 + chunk
    const int n = bz >> 2, chunk = bz & 3;
    const int d0 = chunk * DPC;
    const int dpc = (DOUT - d0 < DPC) ? (DOUT - d0) : DPC;   // 22,22,22,20
    const int NIT = (dpc + KW - 1) >> 1;   // pairs: 16 or 15
    const int h0 = blockIdx.y * HT, w0 = blockIdx.x * WT;

    // 1-D separable profile from marginal sums of the 3-D window.
    if (t < 121) {
        const int i = t / KW, j = t - i * KW;
        const float* wp = win + i * (KW * KW) + j * KW;
        float s = 0.f;
        #pragma unroll
        for (int m = 0; m < KW; ++m) s += wp[m];
        tmpw[t] = s;
    }
    __syncthreads();
    if (t < KW) {
        float s = 0.f;
        #pragma unroll
        for (int j = 0; j < KW; ++j) s += tmpw[t * KW + j];
        w1s[t] = s;
    }
    __syncthreads();
    f32x2 w2[KW];                          // wave-uniform -> SGPR pairs
    #pragma unroll
    for (int k = 0; k < KW; ++k) {
        const float ws = rfl(w1s[k]);
        w2[k] = (f32x2){ws, ws};
    }
    __syncthreads();   // tmpw/w1s region of a4pool free before phase A writes

    // ---- staging task setup: tasks u = t + 256q, u in [0,780) ----
    // u: sl = u>=390, v = u-390sl, r = v/15, rem = v-15r, half = rem>=7,
    // c = rem-7half (c==7 -> row pad, dummy). Dest is linear: float off 4u.
    const float* tp[NSTG];
    int tstr[NSTG];
    #pragma unroll
    for (int q = 0; q < NSTG; ++q) {
        const int u = t + 256 * q;
        const int sl = (u >= SLICE_SLOT) ? 1 : 0;
        const int v = u - sl * SLICE_SLOT;
        const int r = v / ROW_SLOT;
        const int rem = v - r * ROW_SLOT;
        const int half = (rem >= 7) ? 1 : 0;
        const int c = rem - 7 * half;
        const int gh = h0 + r, gw0 = w0 + 4 * c;
        const bool oob = (u >= PAIR_SLOT) || (c >= 7) || (gh >= HI) || (gw0 >= WI);
        const float* base = half ? img2 : img1;
        tp[q] = oob ? img1
                    : base + ((long)(n * DI + d0 + sl) * HSZ + (long)gh * WI + gw0);
        tstr[q] = oob ? 0 : 2 * HSZ;       // advance one pair per issue
    }
    #define STAGE(pb_) do { \
        float* db_ = &rawf[(pb_) * PAIR_F + 4 * t]; \
        gl_lds16(tp[0], db_);          tp[0] += tstr[0]; \
        gl_lds16(tp[1], db_ + 1024);   tp[1] += tstr[1]; \
        gl_lds16(tp[2], db_ + 2048);   tp[2] += tstr[2]; \
        if (t < PAIR_SLOT - 768) { gl_lds16(tp[3], db_ + 3072); tp[3] += tstr[3]; } \
    } while (0)

    // Packed D-conv rings: AB = (mu1,mu2), PQ = (E12, Ess).
    f32x2 rAB[KW], rPQ[KW];
    #pragma unroll
    for (int p = 0; p < KW; ++p) { rAB[p] = (f32x2){0.f,0.f}; rPQ[p] = (f32x2){0.f,0.f}; }

    const int ty = t >> 4, tx = t & 15;
    const bool valid = (h0 + ty < HOUT) && (w0 + tx < WOUT);
    float partial = 0.f;

    // Phase A: one 4-output W-conv task; u in [0,208) = 2 sl x 26 r x 4 cg.
    auto phaseA = [&](int u, int pbA) {
        const int sl = (u >= 104) ? 1 : 0;
        const int v = u - sl * 104;
        const int r = v >> 2, cg = v & 3;
        const float* rb = &rawf[pbA * PAIR_F + sl * SLICE_F + r * 60];
        f32x2 s12[4] = {{0.f,0.f},{0.f,0.f},{0.f,0.f},{0.f,0.f}};
        f32x2 s34[4] = {{0.f,0.f},{0.f,0.f},{0.f,0.f},{0.f,0.f}};
        #pragma unroll
        for (int q = 0; q < 4; ++q) {
            const f32x4 aq = *(const f32x4*)(rb + 4 * (cg + q));        // img1 chunk
            const f32x4 bq = *(const f32x4*)(rb + 28 + 4 * (cg + q));   // img2 chunk
            #pragma unroll
            for (int j = 0; j < 4; ++j) {
                const int m = 4 * q + j;                 // rel col
                if (m < 14) {
                    const float x = aq[j], y = bq[j];
                    const f32x2 pxy = (f32x2){x, y};
                    const f32x2 pts = (f32x2){x * y, fmaf(x, x, y * y)};
                    #pragma unroll
                    for (int o = 0; o < 4; ++o) {
                        const int k = m - o;             // compile-time
                        if (k >= 0 && k <= 10) {
                            s12[o] = pk_fma_s(w2[k], pxy, s12[o]);
                            s34[o] = pk_fma_s(w2[k], pts, s34[o]);
                        }
                    }
                }
            }
        }
        #pragma unroll
        for (int o = 0; o < 4; ++o)
            A4AT(pbA, sl, r, 4 * cg + o) = (f32x4){s12[o].x, s12[o].y, s34[o].x, s34[o].y};
    };

    // ---- prologue: DMA pair0 -> raw[0]; drain; DMA pair1 + A(0); drain ----
    STAGE(0);
    __syncthreads();
    STAGE(1);
    if (t < 208) phaseA(t, 0);
    __syncthreads();

    // ---- pipelined main loop: ONE barrier per pair ----
    // iter i: DMA(pair i+2)->raw[i&1] | B(i) from A4[i&1] | A(i+1)->A4[(i+1)&1]
    int jj = 0;        // (2i) % 11
    for (int i = 0; i < NIT; ++i) {
        if (i + 2 < NIT) STAGE(i & 1);
        const int pb = i & 1;

        // phase B: packed H-conv both slices of pair i
        f32x2 fa12={0.f,0.f}, fa34={0.f,0.f}, fb12={0.f,0.f}, fb34={0.f,0.f};
        #pragma unroll
        for (int kh = 0; kh < KW; ++kh) {
            const f32x4 va = A4AT(pb, 0, ty + kh, tx);
            const f32x4 vb = A4AT(pb, 1, ty + kh, tx);
            fa12 = pk_fma_s(w2[kh], (f32x2){va.x, va.y}, fa12);
            fa34 = pk_fma_s(w2[kh], (f32x2){va.z, va.w}, fa34);
            fb12 = pk_fma_s(w2[kh], (f32x2){vb.x, vb.y}, fb12);
            fb34 = pk_fma_s(w2[kh], (f32x2){vb.z, vb.w}, fb34);
        }

        // phase A of NEXT pair (independent buffers -> same barrier region)
        if (i + 1 < NIT && t < 208) phaseA(t, (i + 1) & 1);

        // D-ring + emit for pair i
        const bool emit = (i >= 5);
        f32x2 oa12={0.f,0.f}, oa34={0.f,0.f}, ob12={0.f,0.f}, ob34={0.f,0.f};
        switch (jj) {
            #define CASE2(J) case J: \
                acc_step<J>(rAB, rPQ, w2, fa12, fa34, emit, oa12, oa34); \
                acc_step<(J+1)%KW>(rAB, rPQ, w2, fb12, fb34, emit, ob12, ob34); \
                break;
            CASE2(0) CASE2(1) CASE2(2) CASE2(3) CASE2(4) CASE2(5)
            CASE2(6) CASE2(7) CASE2(8) CASE2(9) CASE2(10)
            #undef CASE2
        }
        jj += 2; if (jj >= KW) jj -= KW;

        if (emit && valid) {
            {
                const float mu1 = oa12.x, mu2 = oa12.y;
                const float m11 = mu1 * mu1, m22 = mu2 * mu2, m12 = mu1 * mu2;
                const float num = (2.f * m12 + SSIM_C1) * (2.f * (oa34.x - m12) + SSIM_C2);
                const float den = (m11 + m22 + SSIM_C1) * ((oa34.y - m11 - m22) + SSIM_C2);
                partial += num * __builtin_amdgcn_rcpf(den);
            }
            {
                const float mu1 = ob12.x, mu2 = ob12.y;
                const float m11 = mu1 * mu1, m22 = mu2 * mu2, m12 = mu1 * mu2;
                const float num = (2.f * m12 + SSIM_C1) * (2.f * (ob34.x - m12) + SSIM_C2);
                const float den = (m11 + m22 + SSIM_C1) * ((ob34.y - m11 - m22) + SSIM_C2);
                partial += num * __builtin_amdgcn_rcpf(den);
            }
        }
        __syncthreads();   // A4[(i+1)&1] ready; DMA(i+2) drained; B(i) reads done
    }

    // ---- block reduction (red aliases a4pool; A4 dead after final barrier) ----
    #pragma unroll
    for (int off = 32; off >= 1; off >>= 1)
        partial += __shfl_down(partial, off, 64);
    if ((t & 63) == 0) red[t >> 6] = partial;
    __syncthreads();
    if (t == 0) {
        bsum[(blockIdx.z * gridDim.y + blockIdx.y) * gridDim.x + blockIdx.x]
            = red[0] + red[1] + red[2] + red[3];
    }
}

static __global__ __launch_bounds__(256) void ssim_reduce(
    const float* __restrict__ bsum, float* __restrict__ out)
{
    __shared__ double red[4];
    const int t = threadIdx.x;
    double s = 0.0;
    for (int i = t; i < NBLK; i += 256) s += (double)bsum[i];
    #pragma unroll
    for (int off = 32; off >= 1; off >>= 1)
        s += __shfl_down(s, off, 64);
    if ((t & 63) == 0) red[t >> 6] = s;
    __syncthreads();
    if (t == 0) {
        const double tot = red[0] + red[1] + red[2] + red[3];
        out[0] = (float)(tot / (double)((long)NB * DOUT * HOUT * WOUT));
    }
}

extern "C" void kernel_launch(void* const* d_in, const int* in_sizes, int n_in,
                              void* d_out, int out_size, void* d_ws, size_t ws_size,
                              hipStream_t stream)
{
    const float* img1 = (const float*)d_in[0];
    const float* img2 = (const float*)d_in[1];
    const float* win  = (const float*)d_in[2];
    float* out  = (float*)d_out;
    float* bsum = (float*)d_ws;   // 2048 floats = 8 KB scratch

    dim3 grid(16, 16, NB * DCH);
    ssim_main<<<grid, 256, 0, stream>>>(img1, img2, win, bsum);
    ssim_reduce<<<1, 256, 0, stream>>>(bsum, out);
}

// Round 10
// 119.589 us; speedup vs baseline: 1.0639x; 1.0639x over previous
//
#include <hip/hip_runtime.h>

// ---- problem constants ----
#define KW 11
#define NB 2            // N * C
#define DI 96
#define HI 256
#define WI 256
#define DOUT 86
#define HOUT 246
#define WOUT 246
#define HT 16           // output tile height
#define WT 16           // output tile width
#define DCH 4           // chunks along D
#define DPC 22          // output d per chunk (22,22,22,20)
#define RR 26           // HT + KW - 1 region rows
#define HSZ (HI * WI)
#define SSIM_C1 1e-4f
#define SSIM_C2 9e-4f
#define NBLK (16 * 16 * NB * DCH)   // 2048
// raw pair buffer: 2 slices x 26 rows x [7 img1 chunks | 7 img2 chunks | 1 pad]
// x 16B = 780 slots = 12480 B. Row stride 15 slots: phase-A b128 reads spread
// bank-groups as (c - r) mod 8 -> uniform 8 lanes/group = b128 floor (verified
// R9: conflict count equal to XOR layout). Single buffer (R8 structure).
#define ROW_SLOT 15
#define SLICE_SLOT (RR * ROW_SLOT)   // 390
#define PAIR_SLOT (2 * SLICE_SLOT)   // 780
#define SLICE_F (SLICE_SLOT * 4)     // 1560 floats
#define NSTG 4

typedef const unsigned int __attribute__((address_space(1)))* gp1_t;
typedef unsigned int __attribute__((address_space(3)))* lp3_t;
using f32x2 = __attribute__((ext_vector_type(2))) float;
using f32x4 = __attribute__((ext_vector_type(4))) float;

__device__ __forceinline__ void gl_lds16(const float* g, float* l) {
    __builtin_amdgcn_global_load_lds((gp1_t)(const void*)g, (lp3_t)(void*)l, 16, 0, 0);
}

// packed fp32 FMA, wave-uniform weight in SGPR pair.
__device__ __forceinline__ f32x2 pk_fma_s(f32x2 w, f32x2 x, f32x2 acc) {
    f32x2 d;
    asm("v_pk_fma_f32 %0, %1, %2, %3" : "=v"(d) : "s"(w), "v"(x), "v"(acc));
    return d;
}

__device__ __forceinline__ float rfl(float x) {
    return __int_as_float(__builtin_amdgcn_readfirstlane(__float_as_int(x)));
}

// Packed ring-buffer D-conv step, compile-time slot indices.
template<int J>
__device__ __forceinline__ void acc_step(
    f32x2 (&AB)[KW], f32x2 (&PQ)[KW], const f32x2 (&w2)[KW],
    f32x2 f12, f32x2 f34, bool emit, f32x2& o12, f32x2& o34)
{
    #pragma unroll
    for (int p = 0; p < KW; ++p) {
        const int s = (J - p + KW) % KW;   // compile-time
        AB[s] = pk_fma_s(w2[p], f12, AB[s]);
        PQ[s] = pk_fma_s(w2[p], f34, PQ[s]);
    }
    const int C = (J + 1) % KW;
    if (emit) { o12 = AB[C]; o34 = PQ[C]; }
    AB[C] = (f32x2){0.f, 0.f};
    PQ[C] = (f32x2){0.f, 0.f};
}

// NOTE: min-waves/EU = 2 (VGPR cap 256). (256,4) caps VGPRs at 64 -> massive
// spill (R4). Vertical coarsening (2 rings/thread) also spills (R7). Deep
// pipelining w/ dbuf costs occupancy (R9: 53KB LDS -> 3 blk/CU -> regression).
static __global__ __launch_bounds__(256, 2) void ssim_main(
    const float* __restrict__ img1, const float* __restrict__ img2,
    const float* __restrict__ win, float* __restrict__ bsum)
{
    __shared__ __align__(16) float rawf[PAIR_SLOT * 4];      // 12480 B
    __shared__ __align__(16) float a4pool[2 * RR * 17 * 4];  // 14144 B
    // A4[sl][r][c], stride 17 f32x4/row: bank-group (r+c)&7 -> uniform; linear
    // stride keeps phase-B taps as base + immediate ds offsets (no XOR VALU).
    #define A4AT(sl, r, c) (((f32x4*)a4pool)[(((sl) * RR) + (r)) * 17 + (c)])
    // w-profile scratch aliased into a4pool (dead before first phase A);
    // red used only after the final loop barrier.
    float* const tmpw = a4pool;          // 121 floats
    float* const w1s  = a4pool + 128;    // 11 floats
    float* const red  = a4pool + 140;    // 4 floats

    const int t = threadIdx.x;
    const int bz = blockIdx.z;            // n*4 + chunk
    const int n = bz >> 2, chunk = bz & 3;
    const int d0 = chunk * DPC;
    const int dpc = (DOUT - d0 < DPC) ? (DOUT - d0) : DPC;   // 22,22,22,20
    const int NIT = (dpc + KW - 1) >> 1;   // pairs: 16 or 15
    const int h0 = blockIdx.y * HT, w0 = blockIdx.x * WT;

    // 1-D separable profile from marginal sums of the 3-D window.
    if (t < 121) {
        const int i = t / KW, j = t - i * KW;
        const float* wp = win + i * (KW * KW) + j * KW;
        float s = 0.f;
        #pragma unroll
        for (int m = 0; m < KW; ++m) s += wp[m];
        tmpw[t] = s;
    }
    __syncthreads();
    if (t < KW) {
        float s = 0.f;
        #pragma unroll
        for (int j = 0; j < KW; ++j) s += tmpw[t * KW + j];
        w1s[t] = s;
    }
    __syncthreads();
    f32x2 w2[KW];                          // wave-uniform -> SGPR pairs
    #pragma unroll
    for (int k = 0; k < KW; ++k) {
        const float ws = rfl(w1s[k]);
        w2[k] = (f32x2){ws, ws};
    }
    __syncthreads();   // w-scratch region of a4pool free before phase A writes

    // ---- staging task setup: u = t + 256q, u in [0,780) ----
    // slot u: sl = u>=390, v = u-390sl, r = v/15, rem = v-15r, half = rem>=7,
    // c = rem-7half (rem==14 -> row pad, dummy). LDS dest linear: float off 4u.
    const float* tp[NSTG];
    int tstr[NSTG];
    #pragma unroll
    for (int q = 0; q < NSTG; ++q) {
        const int u = t + 256 * q;
        const int sl = (u >= SLICE_SLOT) ? 1 : 0;
        const int v = u - sl * SLICE_SLOT;
        const int r = v / ROW_SLOT;
        const int rem = v - r * ROW_SLOT;
        const int half = (rem >= 7) ? 1 : 0;
        const int c = rem - 7 * half;
        const int gh = h0 + r, gw0 = w0 + 4 * c;
        const bool oob = (u >= PAIR_SLOT) || (c >= 7) || (gh >= HI) || (gw0 >= WI);
        const float* base = half ? img2 : img1;
        tp[q] = oob ? img1
                    : base + ((long)(n * DI + d0 + sl) * HSZ + (long)gh * WI + gw0);
        tstr[q] = oob ? 0 : 2 * HSZ;       // advance one pair per issue
    }
    #define STAGE() do { \
        float* db_ = &rawf[4 * t]; \
        gl_lds16(tp[0], db_);          tp[0] += tstr[0]; \
        gl_lds16(tp[1], db_ + 1024);   tp[1] += tstr[1]; \
        gl_lds16(tp[2], db_ + 2048);   tp[2] += tstr[2]; \
        if (t < PAIR_SLOT - 768) { gl_lds16(tp[3], db_ + 3072); tp[3] += tstr[3]; } \
    } while (0)

    // Packed D-conv rings: AB = (mu1,mu2), PQ = (E12, Ess).
    f32x2 rAB[KW], rPQ[KW];
    #pragma unroll
    for (int p = 0; p < KW; ++p) { rAB[p] = (f32x2){0.f,0.f}; rPQ[p] = (f32x2){0.f,0.f}; }

    const int ty = t >> 4, tx = t & 15;
    const bool valid = (h0 + ty < HOUT) && (w0 + tx < WOUT);
    float partial = 0.f;

    // Phase A: one 4-output W-conv task; u in [0,208) = 2 sl x 26 r x 4 cg.
    auto phaseA = [&](int u) {
        const int sl = (u >= 104) ? 1 : 0;
        const int v = u - sl * 104;
        const int r = v >> 2, cg = v & 3;
        const float* rb = &rawf[sl * SLICE_F + r * 60];
        f32x2 s12[4] = {{0.f,0.f},{0.f,0.f},{0.f,0.f},{0.f,0.f}};
        f32x2 s34[4] = {{0.f,0.f},{0.f,0.f},{0.f,0.f},{0.f,0.f}};
        #pragma unroll
        for (int q = 0; q < 4; ++q) {
            const f32x4 aq = *(const f32x4*)(rb + 4 * (cg + q));        // img1
            const f32x4 bq = *(const f32x4*)(rb + 28 + 4 * (cg + q));   // img2
            #pragma unroll
            for (int j = 0; j < 4; ++j) {
                const int m = 4 * q + j;                 // rel col
                if (m < 14) {
                    const float x = aq[j], y = bq[j];
                    const f32x2 pxy = (f32x2){x, y};
                    const f32x2 pts = (f32x2){x * y, fmaf(x, x, y * y)};
                    #pragma unroll
                    for (int o = 0; o < 4; ++o) {
                        const int k = m - o;             // compile-time
                        if (k >= 0 && k <= 10) {
                            s12[o] = pk_fma_s(w2[k], pxy, s12[o]);
                            s34[o] = pk_fma_s(w2[k], pts, s34[o]);
                        }
                    }
                }
            }
        }
        #pragma unroll
        for (int o = 0; o < 4; ++o)
            A4AT(sl, r, 4 * cg + o) = (f32x4){s12[o].x, s12[o].y, s34[o].x, s34[o].y};
    };

    // ---- prologue: stage slices d0, d0+1 ----
    STAGE();
    __syncthreads();   // drains vmcnt -> raw ready

    int jj = 0;        // (2i) % 11
    for (int i = 0; i < NIT; ++i) {
        // ---- phase A: both slices' W-convs (208 tasks) ----
        if (t < 208) phaseA(t);
        __syncthreads();   // A4 ready; raw fully consumed

        // ---- issue staging for next slice pair (lands during phase B) ----
        if (i + 1 < NIT) STAGE();

        // ---- phase B: packed H-conv both slices, ring x2, emit x2 ----
        f32x2 fa12={0.f,0.f}, fa34={0.f,0.f}, fb12={0.f,0.f}, fb34={0.f,0.f};
        #pragma unroll
        for (int kh = 0; kh < KW; ++kh) {
            const f32x4 va = A4AT(0, ty + kh, tx);
            const f32x4 vb = A4AT(1, ty + kh, tx);
            fa12 = pk_fma_s(w2[kh], (f32x2){va.x, va.y}, fa12);
            fa34 = pk_fma_s(w2[kh], (f32x2){va.z, va.w}, fa34);
            fb12 = pk_fma_s(w2[kh], (f32x2){vb.x, vb.y}, fb12);
            fb34 = pk_fma_s(w2[kh], (f32x2){vb.z, vb.w}, fb34);
        }

        const bool emit = (i >= 5);
        f32x2 oa12={0.f,0.f}, oa34={0.f,0.f}, ob12={0.f,0.f}, ob34={0.f,0.f};
        switch (jj) {
            #define CASE2(J) case J: \
                acc_step<J>(rAB, rPQ, w2, fa12, fa34, emit, oa12, oa34); \
                acc_step<(J+1)%KW>(rAB, rPQ, w2, fb12, fb34, emit, ob12, ob34); \
                break;
            CASE2(0) CASE2(1) CASE2(2) CASE2(3) CASE2(4) CASE2(5)
            CASE2(6) CASE2(7) CASE2(8) CASE2(9) CASE2(10)
            #undef CASE2
        }
        jj += 2; if (jj >= KW) jj -= KW;

        if (emit && valid) {
            {
                const float mu1 = oa12.x, mu2 = oa12.y;
                const float m11 = mu1 * mu1, m22 = mu2 * mu2, m12 = mu1 * mu2;
                const float num = (2.f * m12 + SSIM_C1) * (2.f * (oa34.x - m12) + SSIM_C2);
                const float den = (m11 + m22 + SSIM_C1) * ((oa34.y - m11 - m22) + SSIM_C2);
                partial += num * __builtin_amdgcn_rcpf(den);
            }
            {
                const float mu1 = ob12.x, mu2 = ob12.y;
                const float m11 = mu1 * mu1, m22 = mu2 * mu2, m12 = mu1 * mu2;
                const float num = (2.f * m12 + SSIM_C1) * (2.f * (ob34.x - m12) + SSIM_C2);
                const float den = (m11 + m22 + SSIM_C1) * ((ob34.y - m11 - m22) + SSIM_C2);
                partial += num * __builtin_amdgcn_rcpf(den);
            }
        }
        __syncthreads();   // staged raw complete + A4 consumed
    }

    // ---- block reduction (red aliases a4pool; A4 dead after final barrier) ----
    #pragma unroll
    for (int off = 32; off >= 1; off >>= 1)
        partial += __shfl_down(partial, off, 64);
    if ((t & 63) == 0) red[t >> 6] = partial;
    __syncthreads();
    if (t == 0) {
        bsum[(blockIdx.z * gridDim.y + blockIdx.y) * gridDim.x + blockIdx.x]
            = red[0] + red[1] + red[2] + red[3];
    }
}

static __global__ __launch_bounds__(256) void ssim_reduce(
    const float* __restrict__ bsum, float* __restrict__ out)
{
    __shared__ double red[4];
    const int t = threadIdx.x;
    double s = 0.0;
    for (int i = t; i < NBLK; i += 256) s += (double)bsum[i];
    #pragma unroll
    for (int off = 32; off >= 1; off >>= 1)
        s += __shfl_down(s, off, 64);
    if ((t & 63) == 0) red[t >> 6] = s;
    __syncthreads();
    if (t == 0) {
        const double tot = red[0] + red[1] + red[2] + red[3];
        out[0] = (float)(tot / (double)((long)NB * DOUT * HOUT * WOUT));
    }
}

extern "C" void kernel_launch(void* const* d_in, const int* in_sizes, int n_in,
                              void* d_out, int out_size, void* d_ws, size_t ws_size,
                              hipStream_t stream)
{
    const float* img1 = (const float*)d_in[0];
    const float* img2 = (const float*)d_in[1];
    const float* win  = (const float*)d_in[2];
    float* out  = (float*)d_out;
    float* bsum = (float*)d_ws;   // 2048 floats = 8 KB scratch

    dim3 grid(16, 16, NB * DCH);
    ssim_main<<<grid, 256, 0, stream>>>(img1, img2, win, bsum);
    ssim_reduce<<<1, 256, 0, stream>>>(bsum, out);
}